// Round 1
// baseline (464.935 us; speedup 1.0000x reference)
//
#include <hip/hip_runtime.h>
#include <hip/hip_bf16.h>

typedef __bf16 bf16;
typedef __bf16 bf16x8 __attribute__((ext_vector_type(8)));
typedef float f32x4 __attribute__((ext_vector_type(4)));

// problem sizes
#define NN 8192
#define DIN 128
#define DTH 256
#define DH 64

// workspace layout (bytes)
#define OFF_PACC 0                         // 8192*64 f32 partial aggregation
#define OFF_PDEN (8192*64*4)               // 8192 f32 partial denominators
#define OFF_BN   (OFF_PDEN + 8192*4)       // 256 f32 bn sums (sum, sumsq)
#define OFF_HX   (OFF_BN + 1024)           // 8192*256 bf16 Hx
#define OFF_X2T  (OFF_HX + 8192*256*2)     // 64*8192 bf16 X2 transposed
#define ZERO_BYTES OFF_HX

// ---------------------------------------------------------------------------
// BN statistics: per-feature sum and sum-of-squares via per-block partials.
__global__ __launch_bounds__(256) void k_bn_stats(const float* __restrict__ H,
                                                  float* __restrict__ bns) {
    __shared__ float s1[256], s2[256];
    int t = threadIdx.x;
    int f = t & 127, rh = t >> 7;
    int r0 = blockIdx.x * 32 + rh * 16;
    float a = 0.f, b = 0.f;
#pragma unroll
    for (int rr = 0; rr < 16; ++rr) {
        float x = H[(size_t)(r0 + rr) * DIN + f];
        a += x; b += x * x;
    }
    s1[t] = a; s2[t] = b;
    __syncthreads();
    if (t < 128) {
        atomicAdd(&bns[f], s1[t] + s1[t + 128]);
        atomicAdd(&bns[128 + f], s2[t] + s2[t + 128]);
    }
}

// ---------------------------------------------------------------------------
// BN apply + projections: Hx = Hn@Wt+bt (bf16), out1 = leaky(Hn@W1+b1) (fp32,
// written directly to left half of output), X2T[c][row] = Hn@W2+b2 (bf16).
__global__ __launch_bounds__(256) void k_project(
    const float* __restrict__ H, const float* __restrict__ bns,
    const float* __restrict__ gamma, const float* __restrict__ beta,
    const float* __restrict__ Wt, const float* __restrict__ bt,
    const float* __restrict__ W1, const float* __restrict__ b1,
    const float* __restrict__ W2, const float* __restrict__ b2,
    bf16* __restrict__ Hx, bf16* __restrict__ X2T, float* __restrict__ out)
{
    __shared__ float Hn[16 * 128];
    int t = threadIdx.x;
    int r0 = blockIdx.x * 16;
    {   // BN apply: each thread owns feature f = t&127, rows t>>7 + 2p
        int f = t & 127;
        float mean = bns[f] * (1.f / 8192.f);
        float var  = bns[128 + f] * (1.f / 8192.f) - mean * mean;
        float sc = rsqrtf(var + 1e-5f) * gamma[f];
        float sh = beta[f];
        int rb = t >> 7;
#pragma unroll
        for (int p = 0; p < 8; ++p) {
            int row = rb + p * 2;
            float x = H[(size_t)(r0 + row) * DIN + f];
            Hn[row * 128 + f] = (x - mean) * sc + sh;
        }
    }
    __syncthreads();
    {   // Hx = Hn @ Wt + bt : thread -> 4 rows x 4 cols
        int c0 = t & 63, rg = t >> 6;
        float acc[4][4];
#pragma unroll
        for (int i = 0; i < 4; ++i)
#pragma unroll
            for (int j = 0; j < 4; ++j) acc[i][j] = 0.f;
        for (int k = 0; k < 128; ++k) {
            float h[4];
#pragma unroll
            for (int rr = 0; rr < 4; ++rr) h[rr] = Hn[(rg * 4 + rr) * 128 + k];
#pragma unroll
            for (int cc = 0; cc < 4; ++cc) {
                float wv = Wt[k * DTH + c0 + 64 * cc];
#pragma unroll
                for (int rr = 0; rr < 4; ++rr) acc[rr][cc] += h[rr] * wv;
            }
        }
#pragma unroll
        for (int rr = 0; rr < 4; ++rr) {
            int row = r0 + rg * 4 + rr;
#pragma unroll
            for (int cc = 0; cc < 4; ++cc) {
                int c = c0 + 64 * cc;
                Hx[(size_t)row * DTH + c] = (bf16)(acc[rr][cc] + bt[c]);
            }
        }
    }
    {   // out1 (fp32 exact) and X2T (bf16)
        int c = t & 63, rg = t >> 6;
        float a1[4] = {0,0,0,0}, a2[4] = {0,0,0,0};
        for (int k = 0; k < 128; ++k) {
            float w1 = W1[k * DH + c], w2 = W2[k * DH + c];
#pragma unroll
            for (int rr = 0; rr < 4; ++rr) {
                float h = Hn[(rg * 4 + rr) * 128 + k];
                a1[rr] += h * w1; a2[rr] += h * w2;
            }
        }
#pragma unroll
        for (int rr = 0; rr < 4; ++rr) {
            int row = r0 + rg * 4 + rr;
            float v1 = a1[rr] + b1[c];
            out[(size_t)row * 128 + c] = v1 > 0.f ? v1 : 0.01f * v1;
            X2T[(size_t)c * NN + row] = (bf16)(a2[rr] + b2[c]);
        }
    }
}

// ---------------------------------------------------------------------------
// Fused: S = Hx_i @ Hx_j^T (MFMA), gate w = mask? exp(sigmoid(S)) : 0 with
// diag=exp(1), accumulate denom and w @ X2 (MFMA via per-chunk P round-trip).
// Block = 32 i-rows, j-split in 2 halves (grid 512). Partials -> atomics.
#define LDH 264   // Hx tile LDS row stride (256 + 8 pad, keeps 16B align)
#define LDP 72    // P / X2T LDS row stride (64 + 8 pad)

__global__ __launch_bounds__(256) void k_fused(
    const float* __restrict__ A, const bf16* __restrict__ Hx,
    const bf16* __restrict__ X2T, float* __restrict__ pacc,
    float* __restrict__ pden)
{
    __shared__ __align__(16) bf16 hxi[32 * LDH];   // reused as P after prologue
    __shared__ __align__(16) bf16 hxj[64 * LDH];
    __shared__ __align__(16) bf16 x2t[64 * LDP];
    bf16* P = hxi;

    int t = threadIdx.x;
    int w = t >> 6, l = t & 63;
    int q = l >> 4, li = l & 15;
    int ib = blockIdx.x >> 1, js = blockIdx.x & 1;
    int i0 = ib * 32;
    int jbase = js * 4096;

    // stage Hx_i (32 rows x 256) then preload A-fragments into registers
#pragma unroll
    for (int p = 0; p < 4; ++p) {
        int u = t + p * 256;
        int row = u >> 5, seg = u & 31;
        *(bf16x8*)&hxi[row * LDH + seg * 8] =
            *(const bf16x8*)&Hx[(size_t)(i0 + row) * DTH + seg * 8];
    }
    __syncthreads();
    bf16x8 afrag[2][8];
#pragma unroll
    for (int mb = 0; mb < 2; ++mb)
#pragma unroll
        for (int k = 0; k < 8; ++k)
            afrag[mb][k] = *(const bf16x8*)&hxi[(mb * 16 + li) * LDH + k * 32 + q * 8];
    __syncthreads();   // hxi region now free -> becomes P

    f32x4 agg[2] = {{0,0,0,0},{0,0,0,0}};
    float dpart[8] = {0,0,0,0,0,0,0,0};
    int mb_a = w >> 1, cb0 = (w & 1) * 2;

    for (int ch = 0; ch < 64; ++ch) {
        int j0 = jbase + ch * 64;
        // A mask values for this wave's 16 j-columns (issued early)
        float av[8];
        int jc = j0 + w * 16 + li;
#pragma unroll
        for (int mb = 0; mb < 2; ++mb)
#pragma unroll
            for (int r = 0; r < 4; ++r)
                av[mb * 4 + r] = A[(size_t)(i0 + mb * 16 + q * 4 + r) * NN + jc];
        // stage Hx_j chunk (64 rows x 256)
#pragma unroll
        for (int p = 0; p < 8; ++p) {
            int u = t + p * 256;
            int row = u >> 5, seg = u & 31;
            *(bf16x8*)&hxj[row * LDH + seg * 8] =
                *(const bf16x8*)&Hx[(size_t)(j0 + row) * DTH + seg * 8];
        }
        // stage X2 chunk transposed: x2t[col][j-local]
#pragma unroll
        for (int p = 0; p < 2; ++p) {
            int u = t + p * 256;
            int c = u >> 3, seg = u & 7;
            *(bf16x8*)&x2t[c * LDP + seg * 8] =
                *(const bf16x8*)&X2T[(size_t)c * NN + j0 + seg * 8];
        }
        __syncthreads();

        // S tiles: wave w covers n-tile w, both m-tiles, K=256
        f32x4 s0 = {0,0,0,0}, s1 = {0,0,0,0};
#pragma unroll
        for (int k = 0; k < 8; ++k) {
            bf16x8 bfrag = *(const bf16x8*)&hxj[(w * 16 + li) * LDH + k * 32 + q * 8];
            s0 = __builtin_amdgcn_mfma_f32_16x16x32_bf16(afrag[0][k], bfrag, s0, 0, 0, 0);
            s1 = __builtin_amdgcn_mfma_f32_16x16x32_bf16(afrag[1][k], bfrag, s1, 0, 0, 0);
        }

        // gate + exp, accumulate denom, write P (C-layout -> row-major LDS)
#pragma unroll
        for (int mb = 0; mb < 2; ++mb) {
            f32x4 sv = mb ? s1 : s0;
#pragma unroll
            for (int r = 0; r < 4; ++r) {
                int ig = i0 + mb * 16 + q * 4 + r;
                float s = sv[r];
                float sig = __builtin_amdgcn_rcpf(1.f + __expf(-s));
                float wv = (av[mb * 4 + r] > 0.f) ? __expf(sig) : 0.f;
                if (ig == jc) wv = 2.71828182845904523f;   // exp(1.0) diag
                dpart[mb * 4 + r] += wv;
                P[(mb * 16 + q * 4 + r) * LDP + w * 16 + li] = (bf16)wv;
            }
        }
        __syncthreads();   // P visible to all waves

        // agg += P @ X2chunk : wave w -> rows mb_a*16.., X2 col tiles cb0..cb0+1
#pragma unroll
        for (int ks = 0; ks < 2; ++ks) {
            bf16x8 pa = *(const bf16x8*)&P[(mb_a * 16 + li) * LDP + ks * 32 + q * 8];
#pragma unroll
            for (int cbi = 0; cbi < 2; ++cbi) {
                bf16x8 xb = *(const bf16x8*)&x2t[((cb0 + cbi) * 16 + li) * LDP + ks * 32 + q * 8];
                agg[cbi] = __builtin_amdgcn_mfma_f32_16x16x32_bf16(pa, xb, agg[cbi], 0, 0, 0);
            }
        }
        __syncthreads();   // all LDS reads done before next staging
    }

    // write partial aggregation (each output element owned by 1 wave/block)
#pragma unroll
    for (int cbi = 0; cbi < 2; ++cbi)
#pragma unroll
        for (int r = 0; r < 4; ++r)
            atomicAdd(&pacc[(size_t)(i0 + mb_a * 16 + q * 4 + r) * DH + (cb0 + cbi) * 16 + li],
                      agg[cbi][r]);
    // reduce denom partials across the 16 lanes of each quad-group
#pragma unroll
    for (int idx = 0; idx < 8; ++idx) {
        float v = dpart[idx];
        v += __shfl_xor(v, 1, 64);
        v += __shfl_xor(v, 2, 64);
        v += __shfl_xor(v, 4, 64);
        v += __shfl_xor(v, 8, 64);
        if (li == 0)
            atomicAdd(&pden[i0 + (idx >> 2) * 16 + q * 4 + (idx & 3)], v);
    }
}

// ---------------------------------------------------------------------------
__global__ __launch_bounds__(256) void k_finalize(const float* __restrict__ pacc,
                                                  const float* __restrict__ pden,
                                                  float* __restrict__ out)
{
    int e = blockIdx.x * 256 + threadIdx.x;
    int i = e >> 6, c = e & 63;
    float v = pacc[e] / pden[i];
    out[(size_t)i * 128 + 64 + c] = v > 0.f ? v : 0.01f * v;
}

// ---------------------------------------------------------------------------
extern "C" void kernel_launch(void* const* d_in, const int* in_sizes, int n_in,
                              void* d_out, int out_size, void* d_ws, size_t ws_size,
                              hipStream_t stream)
{
    const float* H     = (const float*)d_in[0];
    const float* A     = (const float*)d_in[1];
    const float* gamma = (const float*)d_in[2];
    const float* beta  = (const float*)d_in[3];
    const float* Wt    = (const float*)d_in[4];
    const float* bt    = (const float*)d_in[5];
    const float* W1    = (const float*)d_in[6];
    const float* b1    = (const float*)d_in[7];
    const float* W2    = (const float*)d_in[8];
    const float* b2    = (const float*)d_in[9];
    float* out = (float*)d_out;

    char* ws = (char*)d_ws;
    float* pacc = (float*)(ws + OFF_PACC);
    float* pden = (float*)(ws + OFF_PDEN);
    float* bns  = (float*)(ws + OFF_BN);
    bf16*  Hx   = (bf16*)(ws + OFF_HX);
    bf16*  X2T  = (bf16*)(ws + OFF_X2T);

    hipMemsetAsync(ws, 0, ZERO_BYTES, stream);
    k_bn_stats<<<256, 256, 0, stream>>>(H, bns);
    k_project<<<512, 256, 0, stream>>>(H, bns, gamma, beta, Wt, bt, W1, b1, W2, b2,
                                       Hx, X2T, out);
    k_fused<<<512, 256, 0, stream>>>(A, Hx, X2T, pacc, pden);
    k_finalize<<<2048, 256, 0, stream>>>(pacc, pden, out);
}